// Round 8
// baseline (167.970 us; speedup 1.0000x reference)
//
#include <hip/hip_runtime.h>
#include <math.h>

typedef float f32x4 __attribute__((ext_vector_type(4)));
typedef short bf16x8 __attribute__((ext_vector_type(8)));
typedef unsigned short u16;

__device__ __forceinline__ u16 f2bf(float f) {
    unsigned u = __builtin_bit_cast(unsigned, f);
    u += 0x7fff + ((u >> 16) & 1);   // RNE
    return (u16)(u >> 16);
}
__device__ __forceinline__ float bf2f(u16 s) {
    unsigned v = ((unsigned)s) << 16;
    return __builtin_bit_cast(float, v);
}
__device__ __forceinline__ void gload16(const void* g, void* l) {
    __builtin_amdgcn_global_load_lds(
        (const __attribute__((address_space(1))) unsigned int*)g,
        (__attribute__((address_space(3))) unsigned int*)l, 16, 0, 0);
}

// ---------------- K1: transpose + L2 normalize -> bf16 ----------------
__global__ __launch_bounds__(256) void k_transpose_norm(const float* __restrict__ x,
                                                        u16* __restrict__ xtn) {
    int b8 = blockIdx.x;   // 0..31
    int hh = blockIdx.y;   // 0..15
    int tid = threadIdx.x; // 256
    __shared__ float tile[8][1032];
    __shared__ float inv[8];
    const float* src = x + (size_t)b8 * 1024 * 128 + hh * 8;
    #pragma unroll
    for (int r = 0; r < 4; ++r) {
        int c = tid * 4 + r;
        const float* p = src + (size_t)c * 128;
        float4 v0 = *(const float4*)(p);
        float4 v1 = *(const float4*)(p + 4);
        tile[0][c] = v0.x; tile[1][c] = v0.y; tile[2][c] = v0.z; tile[3][c] = v0.w;
        tile[4][c] = v1.x; tile[5][c] = v1.y; tile[6][c] = v1.z; tile[7][c] = v1.w;
    }
    __syncthreads();
    int w = tid >> 5, j = tid & 31;
    float s = 0.f;
    #pragma unroll 8
    for (int i = 0; i < 32; ++i) { float v = tile[w][i * 32 + j]; s += v * v; }
    #pragma unroll
    for (int m = 16; m; m >>= 1) s += __shfl_xor(s, m);
    if (j == 0) inv[w] = 1.0f / fmaxf(sqrtf(s), 1e-12f);
    __syncthreads();
    int b = b8 >> 3, t = b8 & 7;
    int c0 = tid * 4;
    for (int w2 = 0; w2 < 8; ++w2) {
        int m = t * 128 + hh * 8 + w2;
        float sc = inv[w2];
        u16* dst = xtn + ((size_t)b * 1024 + m) * 1024;
        ushort4 o;
        o.x = f2bf(tile[w2][c0 + 0] * sc);
        o.y = f2bf(tile[w2][c0 + 1] * sc);
        o.z = f2bf(tile[w2][c0 + 2] * sc);
        o.w = f2bf(tile[w2][c0 + 3] * sc);
        *(ushort4*)(dst + c0) = o;
    }
}

// ---------------- K_prep: f2bf(W_gk) + transpose W_inp -> winpT bf16 [1024 c][2048 e] ----------------
__global__ __launch_bounds__(256) void k_prep(const float* __restrict__ Wgk,
                                              const float* __restrict__ Winp,
                                              u16* __restrict__ wgkb,
                                              u16* __restrict__ winpT) {
    int bid = blockIdx.x, tid = threadIdx.x;
    if (bid < 2048) {
        int i = (bid * 256 + tid) * 4;
        float4 v = *(const float4*)(Wgk + i);
        ushort4 o;
        o.x = f2bf(v.x); o.y = f2bf(v.y); o.z = f2bf(v.z); o.w = f2bf(v.w);
        *(ushort4*)(wgkb + i) = o;
    } else {
        int tb = bid - 2048;            // 0..511
        int er = tb & 31, cr = tb >> 5; // e-tile, c-tile (64x64)
        __shared__ float tile[64][65];
        #pragma unroll
        for (int i = 0; i < 16; ++i) {
            int idx = tid + i * 256;
            int r = idx >> 6, c = idx & 63;
            tile[r][c] = Winp[(size_t)(er * 64 + r) * 1024 + cr * 64 + c];
        }
        __syncthreads();
        #pragma unroll
        for (int i = 0; i < 16; ++i) {
            int idx = tid + i * 256;
            int cc = idx >> 6, rr = idx & 63;
            winpT[(size_t)(cr * 64 + cc) * 2048 + er * 64 + rr] = f2bf(tile[rr][cc]);
        }
    }
}

// ---------------- K2: bf16 MFMA GEMM (BT): C[i,j] = sum_k A[i,k]*B[j,k] ----------------
// BK=64, 8 waves, ring-2 LDS, counted vmcnt, both-sides chunk-XOR swizzle (proven R6/R7).
// Kld = leading dim of A/B rows; Kloop = K extent of this dispatch (split-K via blockIdx.z).
template <int BM, int BN, int WC, int MODE>
__global__ __launch_bounds__(512) void k_mfma_gemm(
    const u16* __restrict__ A, const u16* __restrict__ B,
    float* __restrict__ Cf, u16* __restrict__ Cb,
    const float* __restrict__ bias, int Kld, int Kloop, int N,
    long long zA, long long zB, long long zC)
{
    constexpr int WR = 8 / WC;
    constexpr int WM = BM / WR;
    constexpr int WN = BN / WC;
    constexpr int MR = WM / 16;
    constexpr int NR = WN / 16;
    constexpr int QA = BM / 64;
    constexpr int QB = BN / 64;
    constexpr int S = QA + QB;
    __shared__ u16 As[2][BM * 64];
    __shared__ u16 Bs[2][BN * 64];
    int bz = blockIdx.z;
    A += (size_t)bz * zA; B += (size_t)bz * zB;
    int tid = threadIdx.x, lane = tid & 63, wave = tid >> 6;
    int wr = wave / WC, wc = wave % WC;
    int i0 = blockIdx.y * BM, j0 = blockIdx.x * BN;
    int fr = lane & 15, fg = lane >> 4;
    f32x4 acc[MR][NR] = {};

    int srcOff = ((tid & 7) ^ ((tid >> 3) & 7)) * 8;   // pre-swizzled global chunk

    auto stage = [&](int buf, int t) {
        int kt = t * 64;
        #pragma unroll
        for (int q = 0; q < QA; ++q) {
            int row = (q * 512 + tid) >> 3;
            gload16(A + (size_t)(i0 + row) * Kld + kt + srcOff,
                    &As[buf][(q * 512 + wave * 64) * 8]);
        }
        #pragma unroll
        for (int q = 0; q < QB; ++q) {
            int row = (q * 512 + tid) >> 3;
            gload16(B + (size_t)(j0 + row) * Kld + kt + srcOff,
                    &Bs[buf][(q * 512 + wave * 64) * 8]);
        }
    };
    auto compute = [&](int buf) {
        #pragma unroll
        for (int h = 0; h < 2; ++h) {
            bf16x8 af[MR], bv[NR];
            #pragma unroll
            for (int mi = 0; mi < MR; ++mi) {
                int row = wr * WM + mi * 16 + fr;
                af[mi] = *(const bf16x8*)&As[buf][row * 64 + ((h * 4 + fg) ^ (fr & 7)) * 8];
            }
            #pragma unroll
            for (int ni = 0; ni < NR; ++ni) {
                int row = wc * WN + ni * 16 + fr;
                bv[ni] = *(const bf16x8*)&Bs[buf][row * 64 + ((h * 4 + fg) ^ (fr & 7)) * 8];
            }
            #pragma unroll
            for (int mi = 0; mi < MR; ++mi)
                #pragma unroll
                for (int ni = 0; ni < NR; ++ni)
                    acc[mi][ni] = __builtin_amdgcn_mfma_f32_16x16x32_bf16(
                        af[mi], bv[ni], acc[mi][ni], 0, 0, 0);
        }
    };

    int nk = Kloop >> 6;
    stage(0, 0);
    int cur = 0;
    for (int t = 0; t < nk; ++t) {
        if (t + 1 < nk) {
            stage(cur ^ 1, t + 1);
            if constexpr (S == 6)       asm volatile("s_waitcnt vmcnt(6)" ::: "memory");
            else if constexpr (S == 4)  asm volatile("s_waitcnt vmcnt(4)" ::: "memory");
            else                        asm volatile("s_waitcnt vmcnt(8)" ::: "memory");
        } else {
            asm volatile("s_waitcnt vmcnt(0)" ::: "memory");
        }
        __builtin_amdgcn_s_barrier();
        __builtin_amdgcn_sched_barrier(0);
        compute(cur);
        __builtin_amdgcn_s_barrier();
        cur ^= 1;
    }

    // epilogue: C/D layout col = lane&15, row = (lane>>4)*4 + r  [m89]
    if (MODE == 1) {
        #pragma unroll
        for (int ni = 0; ni < NR; ++ni) {
            int col = j0 + wc * WN + ni * 16 + fr;
            float bvv = bias[col];
            #pragma unroll
            for (int mi = 0; mi < MR; ++mi)
                #pragma unroll
                for (int r = 0; r < 4; ++r) {
                    int row = i0 + wr * WM + mi * 16 + fg * 4 + r;
                    Cb[(size_t)row * N + col] = f2bf(acc[mi][ni][r] + bvv);
                }
        }
    } else {
        float* C2 = Cf + (size_t)bz * zC;
        #pragma unroll
        for (int ni = 0; ni < NR; ++ni) {
            int col = j0 + wc * WN + ni * 16 + fr;
            #pragma unroll
            for (int mi = 0; mi < MR; ++mi)
                #pragma unroll
                for (int r = 0; r < 4; ++r) {
                    int row = i0 + wr * WM + mi * 16 + fg * 4 + r;
                    C2[(size_t)row * N + col] = acc[mi][ni][r];
                }
        }
    }
}

// ---------------- K_wcred: Wc bf16 = sum of 4 split-K partials ----------------
__global__ __launch_bounds__(256) void k_wcred(const float* __restrict__ wcp,
                                               u16* __restrict__ wcb) {
    int i = (blockIdx.x * 256 + threadIdx.x) * 4;
    float4 a = *(const float4*)(wcp + i);
    float4 b = *(const float4*)(wcp + 1048576 + i);
    float4 c = *(const float4*)(wcp + 2097152 + i);
    float4 d = *(const float4*)(wcp + 3145728 + i);
    ushort4 o;
    o.x = f2bf(a.x + b.x + c.x + d.x);
    o.y = f2bf(a.y + b.y + c.y + d.y);
    o.z = f2bf(a.z + b.z + c.z + d.z);
    o.w = f2bf(a.w + b.w + c.w + d.w);
    *(ushort4*)(wcb + i) = o;
}

// ---------------- K_wgeff: partials of Wg_eff[g][c] = sum_e W_g[g][e]*W_inp[e][c] ----------------
__global__ __launch_bounds__(256) void k_wgeff(const float* __restrict__ Winp,
                                               const float* __restrict__ Wg,
                                               float* __restrict__ wgp) {
    int cs = blockIdx.x, es = blockIdx.y;   // c-seg(256) x e-seg(64)
    int tid = threadIdx.x;
    __shared__ float wg_l[8][64];
    #pragma unroll
    for (int i = 0; i < 2; ++i) {
        int idx = tid + i * 256;
        wg_l[idx >> 6][idx & 63] = Wg[(size_t)(idx >> 6) * 2048 + es * 64 + (idx & 63)];
    }
    __syncthreads();
    int c = cs * 256 + tid;
    float acc[8] = {};
    #pragma unroll 4
    for (int e = 0; e < 64; ++e) {
        float v = Winp[(size_t)(es * 64 + e) * 1024 + c];
        #pragma unroll
        for (int g = 0; g < 8; ++g) acc[g] += wg_l[g][e] * v;
    }
    #pragma unroll
    for (int g = 0; g < 8; ++g) wgp[(size_t)es * 8192 + g * 1024 + c] = acc[g];
}

// ---------------- K_wgred: reduce 32 partials; also c_g = W_g . b_inp + b_g ----------------
__global__ __launch_bounds__(256) void k_wgred(const float* __restrict__ wgp,
                                               const float* __restrict__ Wg,
                                               const float* __restrict__ binp,
                                               const float* __restrict__ bg,
                                               float* __restrict__ wge,
                                               float* __restrict__ cg) {
    int idx = blockIdx.x * 256 + threadIdx.x;  // 0..8191
    float s = 0.f;
    for (int es = 0; es < 32; ++es) s += wgp[(size_t)es * 8192 + idx];
    wge[idx] = s;
    if (blockIdx.x == 0 && threadIdx.x < 8) {
        float t = bg[threadIdx.x];
        for (int e = 0; e < 2048; ++e) t += Wg[(size_t)threadIdx.x * 2048 + e] * binp[e];
        cg[threadIdx.x] = t;
    }
}

// ---------------- K_agT: agT[b][g][m] = sigmoid(Wg_eff . xtn[b,m,:] + c_g) ----------------
__global__ __launch_bounds__(256) void k_agT(const u16* __restrict__ xtn,
                                             const float* __restrict__ wge,
                                             const float* __restrict__ cg,
                                             float* __restrict__ agT) {
    int b = blockIdx.x, ms = blockIdx.y;   // (4, 32): 32 m's per block
    int tid = threadIdx.x, w = tid >> 6, lane = tid & 63;
    __shared__ float wgel[8192];
    __shared__ float cgl[8];
    #pragma unroll
    for (int i = 0; i < 8; ++i) {
        int idx = tid + i * 256;
        *(float4*)&wgel[idx * 4] = *(const float4*)&wge[idx * 4];
    }
    if (tid < 8) cgl[tid] = cg[tid];
    __syncthreads();
    for (int r = 0; r < 8; ++r) {
        int m = ms * 32 + w * 8 + r;
        const u16* xr = xtn + ((size_t)b * 1024 + m) * 1024;
        float acc[8] = {};
        #pragma unroll
        for (int i = 0; i < 2; ++i) {
            int c0 = i * 512 + lane * 8;
            bf16x8 hv = *(const bf16x8*)(xr + c0);
            float xf[8];
            #pragma unroll
            for (int j = 0; j < 8; ++j) xf[j] = bf2f((u16)hv[j]);
            #pragma unroll
            for (int g = 0; g < 8; ++g) {
                float4 wa = *(const float4*)&wgel[g * 1024 + c0];
                float4 wb = *(const float4*)&wgel[g * 1024 + c0 + 4];
                acc[g] += xf[0] * wa.x + xf[1] * wa.y + xf[2] * wa.z + xf[3] * wa.w
                        + xf[4] * wb.x + xf[5] * wb.y + xf[6] * wb.z + xf[7] * wb.w;
            }
        }
        #pragma unroll
        for (int g = 0; g < 8; ++g)
            #pragma unroll
            for (int off = 32; off; off >>= 1) acc[g] += __shfl_xor(acc[g], off);
        if (lane < 8)
            agT[((size_t)b * 8 + lane) * 1024 + m] =
                1.f / (1.f + expf(-(acc[lane] + cgl[lane])));
    }
}

// ---------------- K4: softmax over m (lt row slice), * alpha_g, in-place; wsum ----------------
// lt layout: [gk][b*1024 + m]
__global__ __launch_bounds__(256) void k_softmax(float* __restrict__ lt,
                                                 const float* __restrict__ agT,
                                                 float* __restrict__ wsum) {
    int gk = blockIdx.x, b = blockIdx.y;
    int tid = threadIdx.x;
    float* row = lt + (size_t)gk * 4096 + b * 1024;
    int g = gk >> 7;
    const float* ag = agT + ((size_t)b * 8 + g) * 1024;
    __shared__ float red[4], red2[4], red3[4];
    float4 v = *(const float4*)(row + tid * 4);
    float mx = fmaxf(fmaxf(v.x, v.y), fmaxf(v.z, v.w));
    #pragma unroll
    for (int m = 32; m; m >>= 1) mx = fmaxf(mx, __shfl_xor(mx, m));
    if ((tid & 63) == 0) red[tid >> 6] = mx;
    __syncthreads();
    mx = fmaxf(fmaxf(red[0], red[1]), fmaxf(red[2], red[3]));
    float e0 = expf(v.x - mx), e1 = expf(v.y - mx), e2 = expf(v.z - mx), e3 = expf(v.w - mx);
    float s = e0 + e1 + e2 + e3;
    #pragma unroll
    for (int m = 32; m; m >>= 1) s += __shfl_xor(s, m);
    if ((tid & 63) == 0) red2[tid >> 6] = s;
    __syncthreads();
    s = red2[0] + red2[1] + red2[2] + red2[3];
    float invs = 1.f / s;
    float4 a = *(const float4*)(ag + tid * 4);
    float w0 = e0 * invs * a.x, w1 = e1 * invs * a.y, w2 = e2 * invs * a.z, w3 = e3 * invs * a.w;
    float4 o; o.x = w0; o.y = w1; o.z = w2; o.w = w3;
    *(float4*)(row + tid * 4) = o;
    float t = w0 + w1 + w2 + w3;
    #pragma unroll
    for (int m = 32; m; m >>= 1) t += __shfl_xor(t, m);
    if ((tid & 63) == 0) red3[tid >> 6] = t;
    __syncthreads();
    if (tid == 0) wsum[((size_t)b * 8 + g) * 128 + (gk & 127)] = red3[0] + red3[1] + red3[2] + red3[3];
}

// ---------------- K4b: wf[b,g,m] = sum_k Wf[k]*w[b,gk,m];  u = Wf*wsum ----------------
__global__ __launch_bounds__(256) void k_wf_u(const float* __restrict__ wT,
                                              const float* __restrict__ wsum,
                                              const float* __restrict__ Wf,
                                              float* __restrict__ wf, float* __restrict__ u) {
    int ms = blockIdx.x, bg = blockIdx.y;
    int b = bg >> 3, g = bg & 7;
    int tid = threadIdx.x;
    __shared__ float wfl[128];
    __shared__ float part[256];
    if (tid < 128) {
        wfl[tid] = Wf[tid];
        if (ms == 0) u[bg * 128 + tid] = Wf[tid] * wsum[bg * 128 + tid];
    }
    __syncthreads();
    int ml = tid & 127;
    int kh = tid >> 7;
    const float* base = wT + (size_t)(g * 128 + kh * 64) * 4096 + (size_t)b * 1024 + ms * 128;
    float acc = 0.f;
    #pragma unroll 4
    for (int k = 0; k < 64; ++k) acc += wfl[kh * 64 + k] * base[(size_t)k * 4096 + ml];
    part[tid] = acc;
    __syncthreads();
    if (tid < 128) wf[(size_t)bg * 1024 + ms * 128 + ml] = part[tid] + part[tid + 128];
}

// ---------------- K_wfx: wfxp[ms][b][g][c] = sum_{m in seg} wf[b,g,m]*xtn[b,m,c] ----------------
__global__ __launch_bounds__(256) void k_wfx(const u16* __restrict__ xtn,
                                             const float* __restrict__ wf,
                                             float* __restrict__ wfxp) {
    int cs = blockIdx.x, ms = blockIdx.y, b = blockIdx.z;  // (4,8,4)
    int tid = threadIdx.x;
    __shared__ float wfl[8][128];
    #pragma unroll
    for (int i = 0; i < 4; ++i) {
        int idx = tid + i * 256;
        wfl[idx >> 7][idx & 127] = wf[((size_t)b * 8 + (idx >> 7)) * 1024 + ms * 128 + (idx & 127)];
    }
    __syncthreads();
    int c = cs * 256 + tid;
    float acc[8] = {};
    for (int m = 0; m < 128; ++m) {
        float xv = bf2f(xtn[((size_t)b * 1024 + ms * 128 + m) * 1024 + c]);
        #pragma unroll
        for (int g = 0; g < 8; ++g) acc[g] += wfl[g][m] * xv;
    }
    #pragma unroll
    for (int g = 0; g < 8; ++g)
        wfxp[(((size_t)ms * 4 + b) * 8 + g) * 1024 + c] = acc[g];
}

// ---------------- K_vfpart: cs<8: vf += wfx . W_inp^T slice; cs==8: -u.cent + sw*b_inp ----------------
__global__ __launch_bounds__(256) void k_vfpart(const float* __restrict__ wfxp,
                                                const u16* __restrict__ winpT,
                                                const float* __restrict__ u,
                                                const float* __restrict__ cent,
                                                const float* __restrict__ binp,
                                                float* __restrict__ vfp) {
    int g = blockIdx.x, cs = blockIdx.y;  // (8, 9)
    int tid = threadIdx.x;
    if (cs < 8) {
        __shared__ float wfx_l[4][128];
        #pragma unroll
        for (int i = 0; i < 2; ++i) {
            int idx = tid + i * 256;
            int bb = idx >> 7, c2 = idx & 127;
            float s = 0.f;
            #pragma unroll
            for (int msq = 0; msq < 8; ++msq)
                s += wfxp[(((size_t)msq * 4 + bb) * 8 + g) * 1024 + cs * 128 + c2];
            wfx_l[bb][c2] = s;
        }
        __syncthreads();
        int d = tid;
        float acc[4] = {};
        for (int c2 = 0; c2 < 128; ++c2) {
            float wv = bf2f(winpT[(size_t)(cs * 128 + c2) * 2048 + g * 256 + d]);
            #pragma unroll
            for (int bb = 0; bb < 4; ++bb) acc[bb] += wfx_l[bb][c2] * wv;
        }
        #pragma unroll
        for (int bb = 0; bb < 4; ++bb)
            vfp[(((size_t)bb * 8 + g) * 9 + cs) * 256 + d] = acc[bb];
    } else {
        __shared__ float ul[4][128];
        __shared__ float swl[4];
        #pragma unroll
        for (int i = 0; i < 2; ++i) {
            int idx = tid + i * 256;
            ul[idx >> 7][idx & 127] = u[((size_t)(idx >> 7) * 8 + g) * 128 + (idx & 127)];
        }
        __syncthreads();
        if (tid < 4) {
            float s = 0.f;
            for (int k = 0; k < 128; ++k) s += ul[tid][k];
            swl[tid] = s;
        }
        __syncthreads();
        int d = tid;
        float acc[4] = {};
        for (int k = 0; k < 128; ++k) {
            float cv = cent[k * 256 + d];
            #pragma unroll
            for (int bb = 0; bb < 4; ++bb) acc[bb] -= ul[bb][k] * cv;
        }
        float bi = binp[g * 256 + d];
        #pragma unroll
        for (int bb = 0; bb < 4; ++bb)
            vfp[(((size_t)bb * 8 + g) * 9 + 8) * 256 + d] = acc[bb] + swl[bb] * bi;
    }
}

// ---------------- K6: finalize vf, center, trace, S(8x8), rank-8 Newton-Schulz ----------------
#define MM8(DST, P, Q) do { if (act) { float s_ = 0.f; \
    _Pragma("unroll") \
    for (int l_ = 0; l_ < 8; ++l_) s_ += P[ii][l_] * Q[l_][jj]; \
    DST[ii][jj] = s_; } __syncthreads(); } while (0)

__global__ __launch_bounds__(256) void k_finalize(const float* __restrict__ vfp,
                                                  const float* __restrict__ bf,
                                                  float* __restrict__ VcOut,
                                                  float* __restrict__ Wrow,
                                                  float* __restrict__ s0) {
    int b = blockIdx.x;
    int tid = threadIdx.x;  // 256
    __shared__ float Vl[256][9];
    __shared__ float red[256];
    __shared__ float Sm[8][8], W1[8][8], W2[8][8], YmL[8][8], ZmL[8][8], ZYL[8][8], FmL[8][8];
    int d = tid;
    float bfv = bf[0];
    float vfl[8];
    #pragma unroll
    for (int g = 0; g < 8; ++g) {
        float acc = 0.f;
        for (int mc = 0; mc < 9; ++mc)
            acc += vfp[(((size_t)b * 8 + g) * 9 + mc) * 256 + d];
        vfl[g] = acc + bfv;
    }
    float mean = 0.f;
    #pragma unroll
    for (int g = 0; g < 8; ++g) mean += vfl[g];
    mean *= 0.125f;
    float trp = 0.f;
    #pragma unroll
    for (int g = 0; g < 8; ++g) { float v = vfl[g] - mean; Vl[d][g] = v; trp += v * v; }
    red[tid] = trp;
    __syncthreads();
    for (int s = 128; s > 0; s >>= 1) { if (tid < s) red[tid] += red[tid + s]; __syncthreads(); }
    float tr = red[0] * 0.125f;  // trace(cov)
    bool act = tid < 64;
    int ii = (tid >> 3) & 7, jj = tid & 7;
    if (act) {
        float sv = 0.f;
        for (int dd = 0; dd < 256; ++dd) sv += Vl[dd][ii] * Vl[dd][jj];
        Sm[ii][jj] = sv / (8.f * tr);
    }
    __syncthreads();
    if (act) {
        YmL[ii][jj] = (ii == jj ? 1.5f : 0.f) - 0.5f * Sm[ii][jj];
        ZmL[ii][jj] = (ii == jj ? -0.5f : 0.f);
    }
    __syncthreads();
    float ya = 0.f, za = 1.5f;
    MM8(W1, Sm, YmL);
    MM8(W2, ZmL, W1);
    float pa = za * ya;
    if (act) ZYL[ii][jj] = -0.5f * (za * YmL[ii][jj] + ya * ZmL[ii][jj] + W2[ii][jj]);
    __syncthreads();
    float zya = 1.5f - 0.5f * pa;
    MM8(W1, Sm, ZYL);
    MM8(W2, YmL, W1);
    if (act) YmL[ii][jj] = ya * ZYL[ii][jj] + zya * YmL[ii][jj] + W2[ii][jj];
    __syncthreads();
    ya = ya * zya;
    MM8(W1, Sm, ZmL);
    MM8(W2, ZYL, W1);
    if (act) ZmL[ii][jj] = zya * ZmL[ii][jj] + za * ZYL[ii][jj] + W2[ii][jj];
    __syncthreads();
    za = zya * za;
    MM8(W1, Sm, YmL);
    MM8(W2, ZmL, W1);
    float p2a = za * ya;
    if (act) ZYL[ii][jj] = za * YmL[ii][jj] + ya * ZmL[ii][jj] + W2[ii][jj];
    __syncthreads();
    MM8(W1, Sm, ZYL);
    MM8(W2, YmL, W1);
    if (act) FmL[ii][jj] = 0.5f * ((3.f - p2a) * YmL[ii][jj] - ya * ZYL[ii][jj] - W2[ii][jj]);
    __syncthreads();
    float fa = 0.5f * ya * (3.f - p2a);
    float sqtr = sqrtf(tr);
    float scaleF = 1.f / (8.f * sqtr);
    #pragma unroll
    for (int jo = 0; jo < 8; ++jo) {
        float sv = 0.f;
        #pragma unroll
        for (int i = 0; i < 8; ++i) sv += Vl[d][i] * FmL[i][jo];
        Wrow[((size_t)b * 256 + d) * 8 + jo] = sv * scaleF;
    }
    #pragma unroll
    for (int jo = 0; jo < 8; ++jo) VcOut[((size_t)b * 256 + d) * 8 + jo] = Vl[d][jo];
    if (tid == 0) s0[b] = fa * sqtr;
}

// ---------------- K7: triuvec output: R[d,e] = s0*delta + Wrow[d,:].Vc[e,:] ----------------
__global__ __launch_bounds__(256) void k_output(const float* __restrict__ Vc,
                                                const float* __restrict__ Wrow,
                                                const float* __restrict__ s0,
                                                float* __restrict__ out) {
    int dd = blockIdx.x, b = blockIdx.y;
    int e = threadIdx.x;
    __shared__ float Vl[256][9];
    __shared__ float wr[8];
    float4 v0 = *(const float4*)(Vc + ((size_t)b * 256 + e) * 8);
    float4 v1 = *(const float4*)(Vc + ((size_t)b * 256 + e) * 8 + 4);
    Vl[e][0] = v0.x; Vl[e][1] = v0.y; Vl[e][2] = v0.z; Vl[e][3] = v0.w;
    Vl[e][4] = v1.x; Vl[e][5] = v1.y; Vl[e][6] = v1.z; Vl[e][7] = v1.w;
    if (e < 8) wr[e] = Wrow[((size_t)b * 256 + dd) * 8 + e];
    __syncthreads();
    if (e >= dd) {
        float v = (e == dd) ? s0[b] : 0.f;
        #pragma unroll
        for (int j = 0; j < 8; ++j) v += wr[j] * Vl[e][j];
        size_t idx = (size_t)b * 32896 + (size_t)dd * 256 - ((size_t)dd * (dd - 1)) / 2 + (e - dd);
        out[idx] = v;
    }
}

extern "C" void kernel_launch(void* const* d_in, const int* in_sizes, int n_in,
                              void* d_out, int out_size, void* d_ws, size_t ws_size,
                              hipStream_t stream) {
    const float* x    = (const float*)d_in[0];
    const float* cent = (const float*)d_in[1];
    const float* Winp = (const float*)d_in[2];
    const float* binp = (const float*)d_in[3];
    const float* Wg   = (const float*)d_in[4];
    const float* bg   = (const float*)d_in[5];
    const float* Wgk  = (const float*)d_in[6];
    const float* Wf   = (const float*)d_in[8];
    const float* bf   = (const float*)d_in[9];
    float* out = (float*)d_out;
    char* wsb = (char*)d_ws;

    // byte-offset workspace layout
    u16*   xtnb  = (u16*)(wsb);                          // [4096][1024] bf16, 8 MB
    float* lt    = (float*)(wsb + (8ull << 20));         // [1024][4096] f32, 16 MB
    u16*   wgkb  = (u16*)(wsb + (24ull << 20));          // [1024][2048] bf16, 4 MB
    u16*   winpT = (u16*)(wsb + (28ull << 20));          // [1024][2048] bf16, 4 MB
    float* wcp   = (float*)(wsb + (32ull << 20));        // [4][1024][1024] f32, 16 MB
    u16*   wcb   = (u16*)(wsb + (48ull << 20));          // [1024][1024] bf16, 2 MB
    float* misc  = (float*)(wsb + (50ull << 20));
    float* wgp   = misc;               // [32][8][1024]
    float* wge   = wgp + 262144;       // [8][1024]
    float* cg    = wge + 8192;         // [8]
    float* agT   = cg + 8;             // [4][8][1024]
    float* wsum  = agT + 32768;        // [4][8][128]
    float* wf    = wsum + 4096;        // [32][1024]
    float* u     = wf + 32768;         // [32][128]
    float* wfxp  = u + 4096;           // [8][4][8][1024]
    float* vfp   = wfxp + 262144;      // [4][8][9][256]
    float* Vc    = vfp + 73728;
    float* Wr    = Vc + 8192;
    float* s0    = Wr + 8192;

    k_transpose_norm<<<dim3(32, 16), 256, 0, stream>>>(x, xtnb);
    k_prep<<<2560, 256, 0, stream>>>(Wgk, Winp, wgkb, winpT);
    k_wgeff<<<dim3(4, 32), 256, 0, stream>>>(Winp, Wg, wgp);
    k_wgred<<<32, 256, 0, stream>>>(wgp, Wg, binp, bg, wge, cg);
    // Wc = W_gk @ W_inp: M=1024, N=1024, K=2048 split-K (4 x 512) -> f32 partials
    k_mfma_gemm<128, 128, 4, 0><<<dim3(8, 8, 4), 512, 0, stream>>>(
        wgkb, winpT, wcp, nullptr, nullptr, 2048, 512, 1024, 512LL, 512LL, 1048576LL);
    k_wcred<<<1024, 256, 0, stream>>>(wcp, wcb);
    // logits: lt[gk][b*1024+m] = Wc @ xtn^T  (M=1024, N=4096, K=1024)
    // (biases dropped: constant per gk-row, softmax over m is shift-invariant)
    k_mfma_gemm<128, 128, 4, 0><<<dim3(32, 8), 512, 0, stream>>>(
        wcb, xtnb, lt, nullptr, nullptr, 1024, 1024, 4096, 0, 0, 0);
    k_agT<<<dim3(4, 32), 256, 0, stream>>>(xtnb, wge, cg, agT);
    k_softmax<<<dim3(1024, 4), 256, 0, stream>>>(lt, agT, wsum);
    k_wf_u<<<dim3(8, 32), 256, 0, stream>>>(lt, wsum, Wf, wf, u);
    k_wfx<<<dim3(4, 8, 4), 256, 0, stream>>>(xtnb, wf, wfxp);
    k_vfpart<<<dim3(8, 9), 256, 0, stream>>>(wfxp, winpT, u, cent, binp, vfp);
    k_finalize<<<4, 256, 0, stream>>>(vfp, bf, Vc, Wr, s0);
    k_output<<<dim3(256, 4), 256, 0, stream>>>(Vc, Wr, s0, out);
}

// Round 9
// 140.042 us; speedup vs baseline: 1.1994x; 1.1994x over previous
//
#include <hip/hip_runtime.h>
#include <math.h>

typedef float f32x4 __attribute__((ext_vector_type(4)));
typedef short bf16x8 __attribute__((ext_vector_type(8)));
typedef unsigned short u16;

__device__ __forceinline__ u16 f2bf(float f) {
    unsigned u = __builtin_bit_cast(unsigned, f);
    u += 0x7fff + ((u >> 16) & 1);   // RNE
    return (u16)(u >> 16);
}
__device__ __forceinline__ float bf2f(u16 s) {
    unsigned v = ((unsigned)s) << 16;
    return __builtin_bit_cast(float, v);
}
__device__ __forceinline__ void gload16(const void* g, void* l) {
    __builtin_amdgcn_global_load_lds(
        (const __attribute__((address_space(1))) unsigned int*)g,
        (__attribute__((address_space(3))) unsigned int*)l, 16, 0, 0);
}

// ---------------- K1: transpose + L2 normalize -> bf16 ----------------
__global__ __launch_bounds__(256) void k_transpose_norm(const float* __restrict__ x,
                                                        u16* __restrict__ xtn) {
    int b8 = blockIdx.x;   // 0..31
    int hh = blockIdx.y;   // 0..15
    int tid = threadIdx.x; // 256
    __shared__ float tile[8][1032];
    __shared__ float inv[8];
    const float* src = x + (size_t)b8 * 1024 * 128 + hh * 8;
    #pragma unroll
    for (int r = 0; r < 4; ++r) {
        int c = tid * 4 + r;
        const float* p = src + (size_t)c * 128;
        float4 v0 = *(const float4*)(p);
        float4 v1 = *(const float4*)(p + 4);
        tile[0][c] = v0.x; tile[1][c] = v0.y; tile[2][c] = v0.z; tile[3][c] = v0.w;
        tile[4][c] = v1.x; tile[5][c] = v1.y; tile[6][c] = v1.z; tile[7][c] = v1.w;
    }
    __syncthreads();
    int w = tid >> 5, j = tid & 31;
    float s = 0.f;
    #pragma unroll 8
    for (int i = 0; i < 32; ++i) { float v = tile[w][i * 32 + j]; s += v * v; }
    #pragma unroll
    for (int m = 16; m; m >>= 1) s += __shfl_xor(s, m);
    if (j == 0) inv[w] = 1.0f / fmaxf(sqrtf(s), 1e-12f);
    __syncthreads();
    int b = b8 >> 3, t = b8 & 7;
    int c0 = tid * 4;
    for (int w2 = 0; w2 < 8; ++w2) {
        int m = t * 128 + hh * 8 + w2;
        float sc = inv[w2];
        u16* dst = xtn + ((size_t)b * 1024 + m) * 1024;
        ushort4 o;
        o.x = f2bf(tile[w2][c0 + 0] * sc);
        o.y = f2bf(tile[w2][c0 + 1] * sc);
        o.z = f2bf(tile[w2][c0 + 2] * sc);
        o.w = f2bf(tile[w2][c0 + 3] * sc);
        *(ushort4*)(dst + c0) = o;
    }
}

// ---------------- K_prep: f2bf(W_gk) + transpose W_inp -> winpT bf16 [1024 c][2048 e] ----------------
__global__ __launch_bounds__(256) void k_prep(const float* __restrict__ Wgk,
                                              const float* __restrict__ Winp,
                                              u16* __restrict__ wgkb,
                                              u16* __restrict__ winpT) {
    int bid = blockIdx.x, tid = threadIdx.x;
    if (bid < 2048) {
        int i = (bid * 256 + tid) * 4;
        float4 v = *(const float4*)(Wgk + i);
        ushort4 o;
        o.x = f2bf(v.x); o.y = f2bf(v.y); o.z = f2bf(v.z); o.w = f2bf(v.w);
        *(ushort4*)(wgkb + i) = o;
    } else {
        int tb = bid - 2048;            // 0..511
        int er = tb & 31, cr = tb >> 5; // e-tile, c-tile (64x64)
        __shared__ float tile[64][65];
        #pragma unroll
        for (int i = 0; i < 16; ++i) {
            int idx = tid + i * 256;
            int r = idx >> 6, c = idx & 63;
            tile[r][c] = Winp[(size_t)(er * 64 + r) * 1024 + cr * 64 + c];
        }
        __syncthreads();
        #pragma unroll
        for (int i = 0; i < 16; ++i) {
            int idx = tid + i * 256;
            int cc = idx >> 6, rr = idx & 63;
            winpT[(size_t)(cr * 64 + cc) * 2048 + er * 64 + rr] = f2bf(tile[rr][cc]);
        }
    }
}

// ---------------- K2: bf16 MFMA GEMM (BT): C[i,j] = sum_k A[i,k]*B[j,k] ----------------
// BK=64, 8 waves, ring-2 LDS, counted vmcnt, both-sides chunk-XOR swizzle (proven R6/R7).
// MODE 0: f32 out. MODE 1: bf16 out + col bias. MODE 2: bf16 out, no bias.
template <int BM, int BN, int WC, int MODE>
__global__ __launch_bounds__(512) void k_mfma_gemm(
    const u16* __restrict__ A, const u16* __restrict__ B,
    float* __restrict__ Cf, u16* __restrict__ Cb,
    const float* __restrict__ bias, int Kld, int Kloop, int N,
    long long zA, long long zB, long long zC)
{
    constexpr int WR = 8 / WC;
    constexpr int WM = BM / WR;
    constexpr int WN = BN / WC;
    constexpr int MR = WM / 16;
    constexpr int NR = WN / 16;
    constexpr int QA = BM / 64;
    constexpr int QB = BN / 64;
    constexpr int S = QA + QB;
    __shared__ u16 As[2][BM * 64];
    __shared__ u16 Bs[2][BN * 64];
    int bz = blockIdx.z;
    A += (size_t)bz * zA; B += (size_t)bz * zB;
    int tid = threadIdx.x, lane = tid & 63, wave = tid >> 6;
    int wr = wave / WC, wc = wave % WC;
    int i0 = blockIdx.y * BM, j0 = blockIdx.x * BN;
    int fr = lane & 15, fg = lane >> 4;
    f32x4 acc[MR][NR] = {};

    int srcOff = ((tid & 7) ^ ((tid >> 3) & 7)) * 8;   // pre-swizzled global chunk

    auto stage = [&](int buf, int t) {
        int kt = t * 64;
        #pragma unroll
        for (int q = 0; q < QA; ++q) {
            int row = (q * 512 + tid) >> 3;
            gload16(A + (size_t)(i0 + row) * Kld + kt + srcOff,
                    &As[buf][(q * 512 + wave * 64) * 8]);
        }
        #pragma unroll
        for (int q = 0; q < QB; ++q) {
            int row = (q * 512 + tid) >> 3;
            gload16(B + (size_t)(j0 + row) * Kld + kt + srcOff,
                    &Bs[buf][(q * 512 + wave * 64) * 8]);
        }
    };
    auto compute = [&](int buf) {
        #pragma unroll
        for (int h = 0; h < 2; ++h) {
            bf16x8 af[MR], bv[NR];
            #pragma unroll
            for (int mi = 0; mi < MR; ++mi) {
                int row = wr * WM + mi * 16 + fr;
                af[mi] = *(const bf16x8*)&As[buf][row * 64 + ((h * 4 + fg) ^ (fr & 7)) * 8];
            }
            #pragma unroll
            for (int ni = 0; ni < NR; ++ni) {
                int row = wc * WN + ni * 16 + fr;
                bv[ni] = *(const bf16x8*)&Bs[buf][row * 64 + ((h * 4 + fg) ^ (fr & 7)) * 8];
            }
            #pragma unroll
            for (int mi = 0; mi < MR; ++mi)
                #pragma unroll
                for (int ni = 0; ni < NR; ++ni)
                    acc[mi][ni] = __builtin_amdgcn_mfma_f32_16x16x32_bf16(
                        af[mi], bv[ni], acc[mi][ni], 0, 0, 0);
        }
    };

    int nk = Kloop >> 6;
    stage(0, 0);
    int cur = 0;
    for (int t = 0; t < nk; ++t) {
        if (t + 1 < nk) {
            stage(cur ^ 1, t + 1);
            if constexpr (S == 6)       asm volatile("s_waitcnt vmcnt(6)" ::: "memory");
            else if constexpr (S == 4)  asm volatile("s_waitcnt vmcnt(4)" ::: "memory");
            else                        asm volatile("s_waitcnt vmcnt(8)" ::: "memory");
        } else {
            asm volatile("s_waitcnt vmcnt(0)" ::: "memory");
        }
        __builtin_amdgcn_s_barrier();
        __builtin_amdgcn_sched_barrier(0);
        compute(cur);
        __builtin_amdgcn_s_barrier();
        cur ^= 1;
    }

    // epilogue: C/D layout col = lane&15, row = (lane>>4)*4 + r  [m89]
    if (MODE >= 1) {
        #pragma unroll
        for (int ni = 0; ni < NR; ++ni) {
            int col = j0 + wc * WN + ni * 16 + fr;
            float bvv = (MODE == 1) ? bias[col] : 0.f;
            #pragma unroll
            for (int mi = 0; mi < MR; ++mi)
                #pragma unroll
                for (int r = 0; r < 4; ++r) {
                    int row = i0 + wr * WM + mi * 16 + fg * 4 + r;
                    Cb[(size_t)row * N + col] = f2bf(acc[mi][ni][r] + bvv);
                }
        }
    } else {
        float* C2 = Cf + (size_t)bz * zC;
        #pragma unroll
        for (int ni = 0; ni < NR; ++ni) {
            int col = j0 + wc * WN + ni * 16 + fr;
            #pragma unroll
            for (int mi = 0; mi < MR; ++mi)
                #pragma unroll
                for (int r = 0; r < 4; ++r) {
                    int row = i0 + wr * WM + mi * 16 + fg * 4 + r;
                    C2[(size_t)row * N + col] = acc[mi][ni][r];
                }
        }
    }
}

// ---------------- K_wcred: Wc bf16 = sum of 4 split-K partials ----------------
__global__ __launch_bounds__(256) void k_wcred(const float* __restrict__ wcp,
                                               u16* __restrict__ wcb) {
    int i = (blockIdx.x * 256 + threadIdx.x) * 4;
    float4 a = *(const float4*)(wcp + i);
    float4 b = *(const float4*)(wcp + 1048576 + i);
    float4 c = *(const float4*)(wcp + 2097152 + i);
    float4 d = *(const float4*)(wcp + 3145728 + i);
    ushort4 o;
    o.x = f2bf(a.x + b.x + c.x + d.x);
    o.y = f2bf(a.y + b.y + c.y + d.y);
    o.z = f2bf(a.z + b.z + c.z + d.z);
    o.w = f2bf(a.w + b.w + c.w + d.w);
    *(ushort4*)(wcb + i) = o;
}

// ---------------- K_wgeff: partials of Wg_eff[g][c] = sum_e W_g[g][e]*W_inp[e][c] ----------------
__global__ __launch_bounds__(256) void k_wgeff(const float* __restrict__ Winp,
                                               const float* __restrict__ Wg,
                                               float* __restrict__ wgp) {
    int cs = blockIdx.x, es = blockIdx.y;   // c-seg(256) x e-seg(64)
    int tid = threadIdx.x;
    __shared__ float wg_l[8][64];
    #pragma unroll
    for (int i = 0; i < 2; ++i) {
        int idx = tid + i * 256;
        wg_l[idx >> 6][idx & 63] = Wg[(size_t)(idx >> 6) * 2048 + es * 64 + (idx & 63)];
    }
    __syncthreads();
    int c = cs * 256 + tid;
    float acc[8] = {};
    #pragma unroll 4
    for (int e = 0; e < 64; ++e) {
        float v = Winp[(size_t)(es * 64 + e) * 1024 + c];
        #pragma unroll
        for (int g = 0; g < 8; ++g) acc[g] += wg_l[g][e] * v;
    }
    #pragma unroll
    for (int g = 0; g < 8; ++g) wgp[(size_t)es * 8192 + g * 1024 + c] = acc[g];
}

// ---------------- K_wgred: reduce 32 partials; c_g = W_g . b_inp + b_g (wave-parallel) ----------------
__global__ __launch_bounds__(256) void k_wgred(const float* __restrict__ wgp,
                                               const float* __restrict__ Wg,
                                               const float* __restrict__ binp,
                                               const float* __restrict__ bg,
                                               float* __restrict__ wge,
                                               float* __restrict__ cg) {
    int idx = blockIdx.x * 256 + threadIdx.x;  // 0..8191
    float s = 0.f;
    for (int es = 0; es < 32; ++es) s += wgp[(size_t)es * 8192 + idx];
    wge[idx] = s;
    if (blockIdx.x == 0) {
        // 8 groups x 32 lanes: lane-parallel dot W_g[g,:] . b_inp
        int g = threadIdx.x >> 5, sub = threadIdx.x & 31;
        float t = 0.f;
        for (int e = sub; e < 2048; e += 32) t += Wg[(size_t)g * 2048 + e] * binp[e];
        #pragma unroll
        for (int m = 16; m; m >>= 1) t += __shfl_xor(t, m);
        if (sub == 0) cg[g] = t + bg[g];
    }
}

// ---------------- K_agT: agT[b][g][m] = sigmoid(Wg_eff . xtn[b,m,:] + c_g) ----------------
__global__ __launch_bounds__(256) void k_agT(const u16* __restrict__ xtn,
                                             const float* __restrict__ wge,
                                             const float* __restrict__ cg,
                                             float* __restrict__ agT) {
    int b = blockIdx.x, ms = blockIdx.y;   // (4, 32): 32 m's per block
    int tid = threadIdx.x, w = tid >> 6, lane = tid & 63;
    __shared__ float wgel[8192];
    __shared__ float cgl[8];
    #pragma unroll
    for (int i = 0; i < 8; ++i) {
        int idx = tid + i * 256;
        *(float4*)&wgel[idx * 4] = *(const float4*)&wge[idx * 4];
    }
    if (tid < 8) cgl[tid] = cg[tid];
    __syncthreads();
    for (int r = 0; r < 8; ++r) {
        int m = ms * 32 + w * 8 + r;
        const u16* xr = xtn + ((size_t)b * 1024 + m) * 1024;
        float acc[8] = {};
        #pragma unroll
        for (int i = 0; i < 2; ++i) {
            int c0 = i * 512 + lane * 8;
            bf16x8 hv = *(const bf16x8*)(xr + c0);
            float xf[8];
            #pragma unroll
            for (int j = 0; j < 8; ++j) xf[j] = bf2f((u16)hv[j]);
            #pragma unroll
            for (int g = 0; g < 8; ++g) {
                float4 wa = *(const float4*)&wgel[g * 1024 + c0];
                float4 wb = *(const float4*)&wgel[g * 1024 + c0 + 4];
                acc[g] += xf[0] * wa.x + xf[1] * wa.y + xf[2] * wa.z + xf[3] * wa.w
                        + xf[4] * wb.x + xf[5] * wb.y + xf[6] * wb.z + xf[7] * wb.w;
            }
        }
        #pragma unroll
        for (int g = 0; g < 8; ++g)
            #pragma unroll
            for (int off = 32; off; off >>= 1) acc[g] += __shfl_xor(acc[g], off);
        if (lane < 8)
            agT[((size_t)b * 8 + lane) * 1024 + m] =
                1.f / (1.f + expf(-(acc[lane] + cgl[lane])));
    }
}

// ---------------- K_smstat: per (gk,b): mx, invs; u[k] = Wf[k]*invs*sum_m ag*e ----------------
// lt bf16 layout: [gk][b*1024 + m]
__global__ __launch_bounds__(256) void k_smstat(const u16* __restrict__ lt,
                                                const float* __restrict__ agT,
                                                const float* __restrict__ Wf,
                                                float2* __restrict__ mxs,
                                                float* __restrict__ u) {
    int gk = blockIdx.x, b = blockIdx.y;
    int tid = threadIdx.x;
    const u16* row = lt + (size_t)gk * 4096 + b * 1024;
    int g = gk >> 7;
    const float* ag = agT + ((size_t)b * 8 + g) * 1024;
    __shared__ float red[4], red2[4], red3[4];
    ushort4 rv = *(const ushort4*)(row + tid * 4);
    float v0 = bf2f(rv.x), v1 = bf2f(rv.y), v2 = bf2f(rv.z), v3 = bf2f(rv.w);
    float mx = fmaxf(fmaxf(v0, v1), fmaxf(v2, v3));
    #pragma unroll
    for (int m = 32; m; m >>= 1) mx = fmaxf(mx, __shfl_xor(mx, m));
    if ((tid & 63) == 0) red[tid >> 6] = mx;
    __syncthreads();
    mx = fmaxf(fmaxf(red[0], red[1]), fmaxf(red[2], red[3]));
    float e0 = expf(v0 - mx), e1 = expf(v1 - mx), e2 = expf(v2 - mx), e3 = expf(v3 - mx);
    float4 a = *(const float4*)(ag + tid * 4);
    float s = e0 + e1 + e2 + e3;
    float sag = a.x * e0 + a.y * e1 + a.z * e2 + a.w * e3;
    #pragma unroll
    for (int m = 32; m; m >>= 1) { s += __shfl_xor(s, m); sag += __shfl_xor(sag, m); }
    if ((tid & 63) == 0) { red2[tid >> 6] = s; red3[tid >> 6] = sag; }
    __syncthreads();
    if (tid == 0) {
        float st = red2[0] + red2[1] + red2[2] + red2[3];
        float sa = red3[0] + red3[1] + red3[2] + red3[3];
        float invs = 1.f / st;
        mxs[gk * 4 + b] = make_float2(mx, invs);
        u[((size_t)b * 8 + g) * 128 + (gk & 127)] = Wf[gk & 127] * sa * invs;
    }
}

// ---------------- K_wf2: wf[b,g,m] = ag[m] * sum_k (Wf[k]*invs_k)*exp(v-mx_k) ----------------
__global__ __launch_bounds__(256) void k_wf2(const u16* __restrict__ lt,
                                             const float2* __restrict__ mxs,
                                             const float* __restrict__ Wf,
                                             const float* __restrict__ agT,
                                             float* __restrict__ wf) {
    int ms = blockIdx.x, bg = blockIdx.y;  // (8, 32)
    int b = bg >> 3, g = bg & 7;
    int tid = threadIdx.x;
    __shared__ float c1[128], mxl[128];
    __shared__ float part[256];
    if (tid < 128) {
        float2 st = mxs[(g * 128 + tid) * 4 + b];
        mxl[tid] = st.x;
        c1[tid] = Wf[tid] * st.y;
    }
    __syncthreads();
    int ml = tid & 127, kh = tid >> 7;
    const u16* base = lt + (size_t)(g * 128 + kh * 64) * 4096 + b * 1024 + ms * 128;
    float acc = 0.f;
    #pragma unroll 4
    for (int k = 0; k < 64; ++k) {
        float v = bf2f(base[(size_t)k * 4096 + ml]);
        acc += c1[kh * 64 + k] * expf(v - mxl[kh * 64 + k]);
    }
    part[tid] = acc;
    __syncthreads();
    if (tid < 128) {
        float agv = agT[((size_t)b * 8 + g) * 1024 + ms * 128 + tid];
        wf[(size_t)bg * 1024 + ms * 128 + tid] = (part[tid] + part[tid + 128]) * agv;
    }
}

// ---------------- K_wfx: wfxp[ms][b][g][c] = sum_{m in seg} wf[b,g,m]*xtn[b,m,c] ----------------
__global__ __launch_bounds__(256) void k_wfx(const u16* __restrict__ xtn,
                                             const float* __restrict__ wf,
                                             float* __restrict__ wfxp) {
    int cs = blockIdx.x, ms = blockIdx.y, b = blockIdx.z;  // (4,8,4)
    int tid = threadIdx.x;
    __shared__ float wfl[8][128];
    #pragma unroll
    for (int i = 0; i < 4; ++i) {
        int idx = tid + i * 256;
        wfl[idx >> 7][idx & 127] = wf[((size_t)b * 8 + (idx >> 7)) * 1024 + ms * 128 + (idx & 127)];
    }
    __syncthreads();
    int c = cs * 256 + tid;
    float acc[8] = {};
    for (int m = 0; m < 128; ++m) {
        float xv = bf2f(xtn[((size_t)b * 1024 + ms * 128 + m) * 1024 + c]);
        #pragma unroll
        for (int g = 0; g < 8; ++g) acc[g] += wfl[g][m] * xv;
    }
    #pragma unroll
    for (int g = 0; g < 8; ++g)
        wfxp[(((size_t)ms * 4 + b) * 8 + g) * 1024 + c] = acc[g];
}

// ---------------- K_vfpart: cs<8: vf += wfx . W_inp^T slice; cs==8: -u.cent + sw*b_inp ----------------
__global__ __launch_bounds__(256) void k_vfpart(const float* __restrict__ wfxp,
                                                const u16* __restrict__ winpT,
                                                const float* __restrict__ u,
                                                const float* __restrict__ cent,
                                                const float* __restrict__ binp,
                                                float* __restrict__ vfp) {
    int g = blockIdx.x, cs = blockIdx.y;  // (8, 9)
    int tid = threadIdx.x;
    if (cs < 8) {
        __shared__ float wfx_l[4][128];
        #pragma unroll
        for (int i = 0; i < 2; ++i) {
            int idx = tid + i * 256;
            int bb = idx >> 7, c2 = idx & 127;
            float s = 0.f;
            #pragma unroll
            for (int msq = 0; msq < 8; ++msq)
                s += wfxp[(((size_t)msq * 4 + bb) * 8 + g) * 1024 + cs * 128 + c2];
            wfx_l[bb][c2] = s;
        }
        __syncthreads();
        int d = tid;
        float acc[4] = {};
        for (int c2 = 0; c2 < 128; ++c2) {
            float wv = bf2f(winpT[(size_t)(cs * 128 + c2) * 2048 + g * 256 + d]);
            #pragma unroll
            for (int bb = 0; bb < 4; ++bb) acc[bb] += wfx_l[bb][c2] * wv;
        }
        #pragma unroll
        for (int bb = 0; bb < 4; ++bb)
            vfp[(((size_t)bb * 8 + g) * 9 + cs) * 256 + d] = acc[bb];
    } else {
        __shared__ float ul[4][128];
        __shared__ float swl[4];
        #pragma unroll
        for (int i = 0; i < 2; ++i) {
            int idx = tid + i * 256;
            ul[idx >> 7][idx & 127] = u[((size_t)(idx >> 7) * 8 + g) * 128 + (idx & 127)];
        }
        __syncthreads();
        if (tid < 4) {
            float s = 0.f;
            for (int k = 0; k < 128; ++k) s += ul[tid][k];
            swl[tid] = s;
        }
        __syncthreads();
        int d = tid;
        float acc[4] = {};
        for (int k = 0; k < 128; ++k) {
            float cv = cent[k * 256 + d];
            #pragma unroll
            for (int bb = 0; bb < 4; ++bb) acc[bb] -= ul[bb][k] * cv;
        }
        float bi = binp[g * 256 + d];
        #pragma unroll
        for (int bb = 0; bb < 4; ++bb)
            vfp[(((size_t)bb * 8 + g) * 9 + 8) * 256 + d] = acc[bb] + swl[bb] * bi;
    }
}

// ---------------- K6: finalize vf, center, trace, S(8x8), rank-8 Newton-Schulz ----------------
#define MM8(DST, P, Q) do { if (act) { float s_ = 0.f; \
    _Pragma("unroll") \
    for (int l_ = 0; l_ < 8; ++l_) s_ += P[ii][l_] * Q[l_][jj]; \
    DST[ii][jj] = s_; } __syncthreads(); } while (0)

__global__ __launch_bounds__(256) void k_finalize(const float* __restrict__ vfp,
                                                  const float* __restrict__ bf,
                                                  float* __restrict__ VcOut,
                                                  float* __restrict__ Wrow,
                                                  float* __restrict__ s0) {
    int b = blockIdx.x;
    int tid = threadIdx.x;  // 256
    __shared__ float Vl[256][9];
    __shared__ float red[256];
    __shared__ float Sm[8][8], W1[8][8], W2[8][8], YmL[8][8], ZmL[8][8], ZYL[8][8], FmL[8][8];
    int d = tid;
    float bfv = bf[0];
    float vfl[8];
    #pragma unroll
    for (int g = 0; g < 8; ++g) {
        float acc = 0.f;
        for (int mc = 0; mc < 9; ++mc)
            acc += vfp[(((size_t)b * 8 + g) * 9 + mc) * 256 + d];
        vfl[g] = acc + bfv;
    }
    float mean = 0.f;
    #pragma unroll
    for (int g = 0; g < 8; ++g) mean += vfl[g];
    mean *= 0.125f;
    float trp = 0.f;
    #pragma unroll
    for (int g = 0; g < 8; ++g) { float v = vfl[g] - mean; Vl[d][g] = v; trp += v * v; }
    red[tid] = trp;
    __syncthreads();
    for (int s = 128; s > 0; s >>= 1) { if (tid < s) red[tid] += red[tid + s]; __syncthreads(); }
    float tr = red[0] * 0.125f;  // trace(cov)
    bool act = tid < 64;
    int ii = (tid >> 3) & 7, jj = tid & 7;
    if (act) {
        float sv = 0.f;
        for (int dd = 0; dd < 256; ++dd) sv += Vl[dd][ii] * Vl[dd][jj];
        Sm[ii][jj] = sv / (8.f * tr);
    }
    __syncthreads();
    if (act) {
        YmL[ii][jj] = (ii == jj ? 1.5f : 0.f) - 0.5f * Sm[ii][jj];
        ZmL[ii][jj] = (ii == jj ? -0.5f : 0.f);
    }
    __syncthreads();
    float ya = 0.f, za = 1.5f;
    MM8(W1, Sm, YmL);
    MM8(W2, ZmL, W1);
    float pa = za * ya;
    if (act) ZYL[ii][jj] = -0.5f * (za * YmL[ii][jj] + ya * ZmL[ii][jj] + W2[ii][jj]);
    __syncthreads();
    float zya = 1.5f - 0.5f * pa;
    MM8(W1, Sm, ZYL);
    MM8(W2, YmL, W1);
    if (act) YmL[ii][jj] = ya * ZYL[ii][jj] + zya * YmL[ii][jj] + W2[ii][jj];
    __syncthreads();
    ya = ya * zya;
    MM8(W1, Sm, ZmL);
    MM8(W2, ZYL, W1);
    if (act) ZmL[ii][jj] = zya * ZmL[ii][jj] + za * ZYL[ii][jj] + W2[ii][jj];
    __syncthreads();
    za = zya * za;
    MM8(W1, Sm, YmL);
    MM8(W2, ZmL, W1);
    float p2a = za * ya;
    if (act) ZYL[ii][jj] = za * YmL[ii][jj] + ya * ZmL[ii][jj] + W2[ii][jj];
    __syncthreads();
    MM8(W1, Sm, ZYL);
    MM8(W2, YmL, W1);
    if (act) FmL[ii][jj] = 0.5f * ((3.f - p2a) * YmL[ii][jj] - ya * ZYL[ii][jj] - W2[ii][jj]);
    __syncthreads();
    float fa = 0.5f * ya * (3.f - p2a);
    float sqtr = sqrtf(tr);
    float scaleF = 1.f / (8.f * sqtr);
    #pragma unroll
    for (int jo = 0; jo < 8; ++jo) {
        float sv = 0.f;
        #pragma unroll
        for (int i = 0; i < 8; ++i) sv += Vl[d][i] * FmL[i][jo];
        Wrow[((size_t)b * 256 + d) * 8 + jo] = sv * scaleF;
    }
    #pragma unroll
    for (int jo = 0; jo < 8; ++jo) VcOut[((size_t)b * 256 + d) * 8 + jo] = Vl[d][jo];
    if (tid == 0) s0[b] = fa * sqtr;
}

// ---------------- K7: triuvec output: R[d,e] = s0*delta + Wrow[d,:].Vc[e,:] ----------------
__global__ __launch_bounds__(256) void k_output(const float* __restrict__ Vc,
                                                const float* __restrict__ Wrow,
                                                const float* __restrict__ s0,
                                                float* __restrict__ out) {
    int dd = blockIdx.x, b = blockIdx.y;
    int e = threadIdx.x;
    __shared__ float Vl[256][9];
    __shared__ float wr[8];
    float4 v0 = *(const float4*)(Vc + ((size_t)b * 256 + e) * 8);
    float4 v1 = *(const float4*)(Vc + ((size_t)b * 256 + e) * 8 + 4);
    Vl[e][0] = v0.x; Vl[e][1] = v0.y; Vl[e][2] = v0.z; Vl[e][3] = v0.w;
    Vl[e][4] = v1.x; Vl[e][5] = v1.y; Vl[e][6] = v1.z; Vl[e][7] = v1.w;
    if (e < 8) wr[e] = Wrow[((size_t)b * 256 + dd) * 8 + e];
    __syncthreads();
    if (e >= dd) {
        float v = (e == dd) ? s0[b] : 0.f;
        #pragma unroll
        for (int j = 0; j < 8; ++j) v += wr[j] * Vl[e][j];
        size_t idx = (size_t)b * 32896 + (size_t)dd * 256 - ((size_t)dd * (dd - 1)) / 2 + (e - dd);
        out[idx] = v;
    }
}

extern "C" void kernel_launch(void* const* d_in, const int* in_sizes, int n_in,
                              void* d_out, int out_size, void* d_ws, size_t ws_size,
                              hipStream_t stream) {
    const float* x    = (const float*)d_in[0];
    const float* cent = (const float*)d_in[1];
    const float* Winp = (const float*)d_in[2];
    const float* binp = (const float*)d_in[3];
    const float* Wg   = (const float*)d_in[4];
    const float* bg   = (const float*)d_in[5];
    const float* Wgk  = (const float*)d_in[6];
    const float* Wf   = (const float*)d_in[8];
    const float* bf   = (const float*)d_in[9];
    float* out = (float*)d_out;
    char* wsb = (char*)d_ws;

    // byte-offset workspace layout
    u16*   xtnb  = (u16*)(wsb);                          // [4096][1024] bf16, 8 MB
    u16*   ltb   = (u16*)(wsb + (8ull << 20));           // [1024][4096] bf16, 8 MB
    u16*   wgkb  = (u16*)(wsb + (16ull << 20));          // [1024][2048] bf16, 4 MB
    u16*   winpT = (u16*)(wsb + (20ull << 20));          // [1024][2048] bf16, 4 MB
    float* wcp   = (float*)(wsb + (24ull << 20));        // [4][1024][1024] f32, 16 MB
    u16*   wcb   = (u16*)(wsb + (40ull << 20));          // [1024][1024] bf16, 2 MB
    float* misc  = (float*)(wsb + (42ull << 20));
    float* wgp   = misc;               // [32][8][1024]
    float* wge   = wgp + 262144;       // [8][1024]
    float* cg    = wge + 8192;         // [8]
    float* agT   = cg + 8;             // [4][8][1024]
    float2* mxs  = (float2*)(agT + 32768);  // [1024][4]
    float* wf    = (float*)(mxs + 4096);    // [32][1024]
    float* u     = wf + 32768;         // [32][128]
    float* wfxp  = u + 4096;           // [8][4][8][1024]
    float* vfp   = wfxp + 262144;      // [4][8][9][256]
    float* Vc    = vfp + 73728;
    float* Wr    = Vc + 8192;
    float* s0    = Wr + 8192;

    k_transpose_norm<<<dim3(32, 16), 256, 0, stream>>>(x, xtnb);
    k_prep<<<2560, 256, 0, stream>>>(Wgk, Winp, wgkb, winpT);
    k_wgeff<<<dim3(4, 32), 256, 0, stream>>>(Winp, Wg, wgp);
    k_wgred<<<32, 256, 0, stream>>>(wgp, Wg, binp, bg, wge, cg);
    // Wc = W_gk @ W_inp: M=1024, N=1024, K=2048 split-K (4 x 512) -> f32 partials
    k_mfma_gemm<128, 128, 4, 0><<<dim3(8, 8, 4), 512, 0, stream>>>(
        wgkb, winpT, wcp, nullptr, nullptr, 2048, 512, 1024, 512LL, 512LL, 1048576LL);
    k_wcred<<<1024, 256, 0, stream>>>(wcp, wcb);
    // logits: lt[gk][b*1024+m] = Wc @ xtn^T -> bf16  (M=1024, N=4096, K=1024)
    // (biases dropped: constant per gk-row, softmax over m is shift-invariant)
    k_mfma_gemm<128, 128, 4, 2><<<dim3(32, 8), 512, 0, stream>>>(
        wcb, xtnb, nullptr, ltb, nullptr, 1024, 1024, 4096, 0, 0, 0);
    k_agT<<<dim3(4, 32), 256, 0, stream>>>(xtnb, wge, cg, agT);
    k_smstat<<<dim3(1024, 4), 256, 0, stream>>>(ltb, agT, Wf, mxs, u);
    k_wf2<<<dim3(8, 32), 256, 0, stream>>>(ltb, mxs, Wf, agT, wf);
    k_wfx<<<dim3(4, 8, 4), 256, 0, stream>>>(xtnb, wf, wfxp);
    k_vfpart<<<dim3(8, 9), 256, 0, stream>>>(wfxp, winpT, u, cent, binp, vfp);
    k_finalize<<<4, 256, 0, stream>>>(vfp, bf, Vc, Wr, s0);
    k_output<<<dim3(256, 4), 256, 0, stream>>>(Vc, Wr, s0, out);
}